// Round 1
// baseline (215.022 us; speedup 1.0000x reference)
//
#include <hip/hip_runtime.h>
#include <math.h>

// ---------------------------------------------------------------------------
// NB regression log-posterior.
//   out = sum_{n,g} [ lgamma(y+r) - lgamma(r) - lgamma(y+1)
//                     + r*log r + y*lm - (y+r)*log(r+m) ]   (m = exp(lm))
//       + prior(mu) + prior(beta) + prior(softplus(phi))
//   lm = log(s[n]) - norm[n] + (mu_g + X[n,:]·beta[:,g])
// Tolerance is 2% relative of ~2.3e9 -> fast approximations are fine.
// ---------------------------------------------------------------------------

__device__ __forceinline__ float fast_rcp(float x) {
    return __builtin_amdgcn_rcpf(x);
}

// lgamma for x > 0: Stirling for x>=8, recurrence below (max 8 iterations;
// only y<=7 lanes take it, ~1.6% of elements).
__device__ __forceinline__ float lgamma_pos(float x) {
    float lp = 0.0f;
    if (x < 8.0f) {
        float p = x;
        x += 1.0f;
        while (x < 8.0f) { p *= x; x += 1.0f; }
        lp = __logf(p);
    }
    float inv  = fast_rcp(x);
    float inv2 = inv * inv;
    float lx   = __logf(x);
    // (x-1/2)ln x - x + ln(2pi)/2 + 1/(12x) - 1/(360x^3) + 1/(1260x^5)
    float ser = inv * (0.08333333333f + inv2 * (-0.002777777778f + inv2 * 7.936507937e-4f));
    return (x - 0.5f) * lx - x + 0.9189385332f + ser - lp;
}

__device__ __forceinline__ float softplus_f(float x) {
    return fmaxf(x, 0.0f) + log1pf(__expf(-fabsf(x)));
}

__device__ __forceinline__ float wave_reduce(float v) {
#pragma unroll
    for (int off = 32; off; off >>= 1) v += __shfl_down(v, off, 64);
    return v;
}

// ---------------------------------------------------------------------------
// K0: priors. log_normal(x,0,2) = -0.5*log(8*pi) - x^2/8
//     log_gamma(sp,2,1) = log(sp) - sp   (lgamma(2)=0)
// ---------------------------------------------------------------------------
__global__ __launch_bounds__(256) void prior_kernel(
        const float* __restrict__ mu, const float* __restrict__ beta,
        const float* __restrict__ phi, double* __restrict__ acc, int P, int G) {
    int g = blockIdx.x * 256 + threadIdx.x;
    float v = 0.0f;
    if (g < G) {
        const float cn = -1.6120857137646180f;  // -0.5*log(8*pi)
        float m = mu[g];
        v = cn - m * m * 0.125f;
        for (int p = 0; p < P; ++p) {
            float b = beta[(size_t)p * G + g];
            v += cn - b * b * 0.125f;
        }
        float sp = softplus_f(phi[g]);
        v += __logf(sp) - sp;
    }
    v = wave_reduce(v);
    __shared__ float red[4];
    int lane = threadIdx.x & 63, wid = threadIdx.x >> 6;
    if (lane == 0) red[wid] = v;
    __syncthreads();
    if (threadIdx.x == 0)
        atomicAdd(acc, (double)(red[0] + red[1] + red[2] + red[3]));
}

// ---------------------------------------------------------------------------
// K1: per-row stats. dc[n] = log(sum_g Y[n,g]) - log(sum_g exp(lu[n,g]))
// One block per row; coalesced Y row read; lu magnitudes are O(10) so the
// un-shifted logsumexp cannot overflow fp32.
// ---------------------------------------------------------------------------
template <int PP>
__global__ __launch_bounds__(256) void row_stats_kernel(
        const float* __restrict__ X, const float* __restrict__ Y,
        const float* __restrict__ mu, const float* __restrict__ beta,
        float* __restrict__ dc, int N, int P, int G) {
    const int n = blockIdx.x;
    const int tid = threadIdx.x;
    const int PR = (PP > 0) ? PP : P;
    float xs[(PP > 0) ? PP : 8];
    for (int p = 0; p < PR; ++p) xs[p] = X[(size_t)n * P + p];
    const float* __restrict__ Yrow = Y + (size_t)n * G;
    float sy = 0.0f, se = 0.0f;
    for (int g = tid; g < G; g += 256) {
        sy += Yrow[g];
        float lu = mu[g];
#pragma unroll
        for (int p = 0; p < PR; ++p) lu += xs[p] * beta[(size_t)p * G + g];
        se += __expf(lu);
    }
    sy = wave_reduce(sy);
    se = wave_reduce(se);
    __shared__ float r1[4], r2[4];
    int lane = tid & 63, wid = tid >> 6;
    if (lane == 0) { r1[wid] = sy; r2[wid] = se; }
    __syncthreads();
    if (tid == 0) {
        float a = r1[0] + r1[1] + r1[2] + r1[3];
        float b = r2[0] + r2[1] + r2[2] + r2[3];
        dc[n] = __logf(a) - __logf(b);
    }
}

// ---------------------------------------------------------------------------
// K2: likelihood. Thread = one gene column (beta/mu/r/cg live in registers),
// loop over a 64-row slab (X, dc staged in LDS; lgamma(y+1) table in LDS).
// Y access: lane i reads Y[n, g0+i] -> 256B coalesced per wave per row.
// ---------------------------------------------------------------------------
#define RPB 64   // rows per block (gridDim.y slabs)

template <int PP>
__global__ __launch_bounds__(256) void nb_loglik_kernel(
        const float* __restrict__ X, const float* __restrict__ Y,
        const float* __restrict__ mu, const float* __restrict__ beta,
        const float* __restrict__ phi, const float* __restrict__ dc,
        double* __restrict__ acc, int N, int P, int G) {
    __shared__ float lgY[512];       // lgamma(i+1)
    __shared__ float Xs[RPB * 8];
    __shared__ float dcs[RPB];

    const int tid = threadIdx.x;
    const int PR = (PP > 0) ? PP : P;
    const int n0 = blockIdx.y * RPB;
    const int nrows = min(RPB, N - n0);

    for (int i = tid; i < 512; i += 256) lgY[i] = lgamma_pos((float)(i + 1));
    for (int i = tid; i < nrows * PR; i += 256) {
        int rr = i / PR, pp = i - rr * PR;
        Xs[rr * PR + pp] = X[(size_t)(n0 + rr) * P + pp];
    }
    for (int i = tid; i < nrows; i += 256) dcs[i] = dc[n0 + i];

    const int g = blockIdx.x * 256 + tid;
    const bool active = (g < G);
    float bb[(PP > 0) ? PP : 8];
    float mug = 0.0f, r = 1.0f, cg = 0.0f;
    if (active) {
        for (int p = 0; p < PR; ++p) bb[p] = beta[(size_t)p * G + g];
        mug = mu[g];
        float sp = softplus_f(phi[g]);
        r = 1.0f / sp;
        cg = r * __logf(r) - lgamma_pos(r);
    }
    __syncthreads();

    float accl = 0.0f;
    if (active) {
        const float* __restrict__ yp = Y + (size_t)n0 * G + g;
#pragma unroll 2
        for (int i = 0; i < nrows; ++i) {
            float lu = mug;
#pragma unroll
            for (int p = 0; p < PR; ++p) lu += Xs[i * PR + p] * bb[p];
            float lm = dcs[i] + lu;
            float m  = __expf(lm);
            float y  = *yp;
            yp += G;
            float yr = y + r;
            float lt = __logf(r + m);
            float lg = lgamma_pos(yr);
            int yi = min((int)y, 511);
            accl += (lg - lgY[yi]) + (y * lm - yr * lt) + cg;
        }
    }
    accl = wave_reduce(accl);
    __shared__ float red[4];
    int lane = tid & 63, wid = tid >> 6;
    if (lane == 0) red[wid] = accl;
    __syncthreads();
    if (tid == 0)
        atomicAdd(acc, (double)(red[0] + red[1] + red[2] + red[3]));
}

__global__ void finalize_kernel(const double* __restrict__ acc, float* __restrict__ out) {
    out[0] = (float)acc[0];
}

// ---------------------------------------------------------------------------
extern "C" void kernel_launch(void* const* d_in, const int* in_sizes, int n_in,
                              void* d_out, int out_size, void* d_ws, size_t ws_size,
                              hipStream_t stream) {
    const float* X    = (const float*)d_in[0];
    const float* Y    = (const float*)d_in[1];
    const float* mu   = (const float*)d_in[2];
    const float* beta = (const float*)d_in[3];
    const float* phi  = (const float*)d_in[4];
    float* out = (float*)d_out;

    const int G = in_sizes[2];
    const int N = in_sizes[1] / G;
    const int P = in_sizes[0] / N;

    double* acc = (double*)d_ws;                      // 8 B accumulator
    float*  dc  = (float*)((char*)d_ws + 256);        // [N] row constants

    hipMemsetAsync(d_ws, 0, 256, stream);             // zero the accumulator

    int gblocks = (G + 255) / 256;
    prior_kernel<<<gblocks, 256, 0, stream>>>(mu, beta, phi, acc, P, G);

    if (P == 4) {
        row_stats_kernel<4><<<N, 256, 0, stream>>>(X, Y, mu, beta, dc, N, P, G);
        dim3 grid2(gblocks, (N + RPB - 1) / RPB);
        nb_loglik_kernel<4><<<grid2, 256, 0, stream>>>(X, Y, mu, beta, phi, dc, acc, N, P, G);
    } else {
        row_stats_kernel<0><<<N, 256, 0, stream>>>(X, Y, mu, beta, dc, N, P, G);
        dim3 grid2(gblocks, (N + RPB - 1) / RPB);
        nb_loglik_kernel<0><<<grid2, 256, 0, stream>>>(X, Y, mu, beta, phi, dc, acc, N, P, G);
    }

    finalize_kernel<<<1, 1, 0, stream>>>(acc, out);
}

// Round 2
// 209.534 us; speedup vs baseline: 1.0262x; 1.0262x over previous
//
#include <hip/hip_runtime.h>
#include <math.h>

// ---------------------------------------------------------------------------
// NB regression log-posterior.
//   out = sum_{n,g} [ lgamma(y+r) - lgamma(r) - lgamma(y+1)
//                     + r*log r + y*lm - (y+r)*log(r+m) ]   (m = exp(lm))
//       + prior(mu) + prior(beta) + prior(softplus(phi))
//   lm = dc[n] + (mu_g + X[n,:]·beta[:,g]),  dc[n] = log(s_n) - logsumexp_g
// Tolerance: 2% relative of ~2.3e9 total -> per-element bias budget ~2.2,
// so fast transcendentals + 2-term Stirling are far within budget.
// ---------------------------------------------------------------------------

#define RPB 16   // rows per nb_loglik block

__device__ __forceinline__ float fast_rcp(float x) {
    return __builtin_amdgcn_rcpf(x);
}

// Accurate-ish lgamma (setup only): recurrence to x>=8 + 3-term Stirling.
__device__ __forceinline__ float lgamma_pos(float x) {
    float lp = 0.0f;
    if (x < 8.0f) {
        float p = x;
        x += 1.0f;
        while (x < 8.0f) { p *= x; x += 1.0f; }
        lp = __logf(p);
    }
    float inv  = fast_rcp(x);
    float inv2 = inv * inv;
    float ser = inv * (0.08333333333f + inv2 * (-0.002777777778f + inv2 * 7.936507937e-4f));
    return (x - 0.5f) * __logf(x) - x + 0.9189385332f + ser - lp;
}

// Hot-loop lgamma: branchless 2-term Stirling. |err| < 0.01 for x>=0.5,
// <2e-4 for x>=1.4 (typical smallest arg), ~0.1 only for the ~1e-5 fraction
// of elements with x<0.4 -- negligible vs the 4.6e7 absolute threshold.
__device__ __forceinline__ float stirling_lg(float x) {
    float inv  = fast_rcp(x);
    float inv2 = inv * inv;
    float ser  = inv * (0.08333333333f - 0.002777777778f * inv2);
    return (x - 0.5f) * __logf(x) - x + 0.9189385332f + ser;
}

__device__ __forceinline__ float softplus_f(float x) {
    return fmaxf(x, 0.0f) + log1pf(__expf(-fabsf(x)));
}

__device__ __forceinline__ float wave_reduce(float v) {
#pragma unroll
    for (int off = 32; off; off >>= 1) v += __shfl_down(v, off, 64);
    return v;
}

// per-element NB log-likelihood term (minus the per-gene/per-count constants
// handled via cg and the lgY table)
__device__ __forceinline__ float nb_elem(float y, float lm, float r, float cg,
                                         const float* __restrict__ lgY) {
    float m  = __expf(lm);
    float yr = y + r;
    float lt = __logf(r + m);
    float lg = stirling_lg(yr);
    int   yi = min(__float2int_rz(y), 511);
    return (lg - lgY[yi]) + fmaf(y, lm, -yr * lt) + cg;
}

// ---------------------------------------------------------------------------
// K0 setup: priors + per-gene r[g], cg[g] + global lgamma(y+1) table.
//   log_normal(x,0,2) = -0.5*log(8*pi) - x^2/8
//   log_gamma(sp,2,1) = log(sp) - sp
// ---------------------------------------------------------------------------
__global__ __launch_bounds__(256) void setup_kernel(
        const float* __restrict__ mu, const float* __restrict__ beta,
        const float* __restrict__ phi, double* __restrict__ acc,
        float* __restrict__ rg, float* __restrict__ cgw,
        float* __restrict__ lgYw, int P, int G) {
    int g = blockIdx.x * 256 + threadIdx.x;
    if (blockIdx.x == 0) {
        for (int i = threadIdx.x; i < 512; i += 256)
            lgYw[i] = lgamma_pos((float)(i + 1));
    }
    float v = 0.0f;
    if (g < G) {
        const float cn = -1.6120857137646180f;  // -0.5*log(8*pi)
        float m = mu[g];
        v = cn - m * m * 0.125f;
        for (int p = 0; p < P; ++p) {
            float b = beta[(size_t)p * G + g];
            v += cn - b * b * 0.125f;
        }
        float sp = softplus_f(phi[g]);
        v += __logf(sp) - sp;
        float r = 1.0f / sp;
        rg[g]  = r;
        cgw[g] = r * __logf(r) - lgamma_pos(r);
    }
    v = wave_reduce(v);
    __shared__ float red[4];
    int lane = threadIdx.x & 63, wid = threadIdx.x >> 6;
    if (lane == 0) red[wid] = v;
    __syncthreads();
    if (threadIdx.x == 0)
        atomicAdd(acc, (double)((red[0] + red[1]) + (red[2] + red[3])));
}

// ---------------------------------------------------------------------------
// K1 row stats: dc[n] = log(sum_g Y) - log(sum_g exp(lu)). One block per row,
// 512 threads, float4 over genes. lu is O(10) so unshifted lse is safe.
// ---------------------------------------------------------------------------
template <int PP>
__global__ __launch_bounds__(512) void row_stats_kernel(
        const float* __restrict__ X, const float* __restrict__ Y,
        const float* __restrict__ mu, const float* __restrict__ beta,
        float* __restrict__ dc, int N, int P, int G) {
    const int n = blockIdx.x;
    const int tid = threadIdx.x;
    const int PR = (PP > 0) ? PP : P;
    const int G4 = G >> 2;
    float xs[(PP > 0) ? PP : 8];
    for (int p = 0; p < PR; ++p) xs[p] = X[(size_t)n * P + p];
    const float4* __restrict__ Y4 = (const float4*)(Y + (size_t)n * G);
    const float4* __restrict__ M4 = (const float4*)mu;
    const float4* __restrict__ B4 = (const float4*)beta;
    float sy = 0.0f, se = 0.0f;
#pragma unroll 2
    for (int i = tid; i < G4; i += 512) {
        float4 y  = Y4[i];
        float4 lu = M4[i];
#pragma unroll
        for (int p = 0; p < PR; ++p) {
            float4 b = B4[(size_t)p * G4 + i];
            lu.x = fmaf(xs[p], b.x, lu.x);
            lu.y = fmaf(xs[p], b.y, lu.y);
            lu.z = fmaf(xs[p], b.z, lu.z);
            lu.w = fmaf(xs[p], b.w, lu.w);
        }
        se += (__expf(lu.x) + __expf(lu.y)) + (__expf(lu.z) + __expf(lu.w));
        sy += (y.x + y.y) + (y.z + y.w);
    }
    sy = wave_reduce(sy);
    se = wave_reduce(se);
    __shared__ float r1[8], r2[8];
    int lane = tid & 63, wid = tid >> 6;
    if (lane == 0) { r1[wid] = sy; r2[wid] = se; }
    __syncthreads();
    if (tid == 0) {
        float a = 0.0f, b = 0.0f;
        for (int w = 0; w < 8; ++w) { a += r1[w]; b += r2[w]; }
        dc[n] = __logf(a) - __logf(b);
    }
}

// ---------------------------------------------------------------------------
// K2 likelihood: thread owns 4 consecutive genes (float4), loops RPB rows.
// Per-gene constants (beta, mu, r, cg) in registers; X rows + dc + lgamma
// table in LDS. Last finished block writes the final scalar.
// ---------------------------------------------------------------------------
template <int PP>
__global__ __launch_bounds__(256) void nb_loglik_kernel(
        const float* __restrict__ X, const float* __restrict__ Y,
        const float* __restrict__ mu, const float* __restrict__ beta,
        const float* __restrict__ rg, const float* __restrict__ cgw,
        const float* __restrict__ lgYw, const float* __restrict__ dc,
        double* __restrict__ acc, float* __restrict__ out,
        unsigned int* __restrict__ counter,
        int N, int P, int G, int nBlocks) {
    __shared__ float lgY[512];
    __shared__ float Xs[RPB * 8];
    __shared__ float dcs[RPB];

    const int tid = threadIdx.x;
    const int PR = (PP > 0) ? PP : P;
    const int n0 = blockIdx.y * RPB;
    const int nrows = min(RPB, N - n0);
    const int G4 = G >> 2;

    for (int i = tid; i < 512; i += 256) lgY[i] = lgYw[i];
    for (int i = tid; i < nrows * PR; i += 256) {
        int rr = i / PR, pp = i - rr * PR;
        Xs[rr * PR + pp] = X[(size_t)(n0 + rr) * P + pp];
    }
    for (int i = tid; i < nrows; i += 256) dcs[i] = dc[n0 + i];

    const int gi = blockIdx.x * 256 + tid;     // float4 index over genes
    const bool active = (gi < G4);
    float4 bb[(PP > 0) ? PP : 8];
    float4 mug = {0, 0, 0, 0}, r4 = {1, 1, 1, 1}, cg4 = {0, 0, 0, 0};
    if (active) {
        const float4* __restrict__ B4 = (const float4*)beta;
        for (int p = 0; p < PR; ++p) bb[p] = B4[(size_t)p * G4 + gi];
        mug = ((const float4*)mu)[gi];
        r4  = ((const float4*)rg)[gi];
        cg4 = ((const float4*)cgw)[gi];
    }
    __syncthreads();

    float a0 = 0.0f, a1 = 0.0f, a2 = 0.0f, a3 = 0.0f;
    if (active) {
        const float4* __restrict__ Yp = (const float4*)Y + (size_t)n0 * G4 + gi;
#pragma unroll 2
        for (int i = 0; i < nrows; ++i) {
            float4 y = *Yp;
            Yp += G4;
            float dcn = dcs[i];
            float4 lu = mug;
#pragma unroll
            for (int p = 0; p < PR; ++p) {
                float xp = Xs[i * PR + p];
                lu.x = fmaf(xp, bb[p].x, lu.x);
                lu.y = fmaf(xp, bb[p].y, lu.y);
                lu.z = fmaf(xp, bb[p].z, lu.z);
                lu.w = fmaf(xp, bb[p].w, lu.w);
            }
            a0 += nb_elem(y.x, dcn + lu.x, r4.x, cg4.x, lgY);
            a1 += nb_elem(y.y, dcn + lu.y, r4.y, cg4.y, lgY);
            a2 += nb_elem(y.z, dcn + lu.z, r4.z, cg4.z, lgY);
            a3 += nb_elem(y.w, dcn + lu.w, r4.w, cg4.w, lgY);
        }
    }
    float accl = (a0 + a1) + (a2 + a3);
    accl = wave_reduce(accl);
    __shared__ float red[4];
    int lane = tid & 63, wid = tid >> 6;
    if (lane == 0) red[wid] = accl;
    __syncthreads();
    if (tid == 0) {
        atomicAdd(acc, (double)((red[0] + red[1]) + (red[2] + red[3])));
        __threadfence();
        unsigned int old = atomicAdd(counter, 1u);
        if (old == (unsigned int)(nBlocks - 1)) {
            double v = atomicAdd(acc, 0.0);   // coherent read of final sum
            out[0] = (float)v;
        }
    }
}

// ---------------------------------------------------------------------------
extern "C" void kernel_launch(void* const* d_in, const int* in_sizes, int n_in,
                              void* d_out, int out_size, void* d_ws, size_t ws_size,
                              hipStream_t stream) {
    const float* X    = (const float*)d_in[0];
    const float* Y    = (const float*)d_in[1];
    const float* mu   = (const float*)d_in[2];
    const float* beta = (const float*)d_in[3];
    const float* phi  = (const float*)d_in[4];
    float* out = (float*)d_out;

    const int G = in_sizes[2];
    const int N = in_sizes[1] / G;
    const int P = in_sizes[0] / N;
    const int G4 = G >> 2;

    // ws layout (offsets 16B-aligned where vector-loaded):
    //   0:    double acc
    //   64:   unsigned counter
    //   256:  lgY table [512]
    //   2304: dc [N]
    //   8192: rg [G]
    //   8192+4G: cg [G]
    char* ws = (char*)d_ws;
    double*       acc     = (double*)ws;
    unsigned int* counter = (unsigned int*)(ws + 64);
    float*        lgYw    = (float*)(ws + 256);
    float*        dcw     = (float*)(ws + 2304);
    float*        rgw     = (float*)(ws + 8192);
    float*        cgw     = (float*)(ws + 8192 + (size_t)4 * G);

    hipMemsetAsync(d_ws, 0, 256, stream);   // acc + counter

    int gblocks = (G + 255) / 256;
    setup_kernel<<<gblocks, 256, 0, stream>>>(mu, beta, phi, acc, rgw, cgw, lgYw, P, G);

    dim3 grid2((G4 + 255) / 256, (N + RPB - 1) / RPB);
    int nBlocks = grid2.x * grid2.y;
    if (P == 4) {
        row_stats_kernel<4><<<N, 512, 0, stream>>>(X, Y, mu, beta, dcw, N, P, G);
        nb_loglik_kernel<4><<<grid2, 256, 0, stream>>>(X, Y, mu, beta, rgw, cgw,
                                                       lgYw, dcw, acc, out, counter,
                                                       N, P, G, nBlocks);
    } else {
        row_stats_kernel<0><<<N, 512, 0, stream>>>(X, Y, mu, beta, dcw, N, P, G);
        nb_loglik_kernel<0><<<grid2, 256, 0, stream>>>(X, Y, mu, beta, rgw, cgw,
                                                       lgYw, dcw, acc, out, counter,
                                                       N, P, G, nBlocks);
    }
}

// Round 3
// 185.452 us; speedup vs baseline: 1.1594x; 1.1299x over previous
//
#include <hip/hip_runtime.h>
#include <math.h>

// ---------------------------------------------------------------------------
// NB regression log-posterior.
//   out = sum_{n,g} [ lgamma(y+r) - lgamma(r) - lgamma(y+1)
//                     + r*log r + y*lm - (y+r)*log(r+m) ]   (m = exp(lm))
//       + prior(mu) + prior(beta) + prior(softplus(phi))
//   lm = dc[n] + (mu_g + X[n,:]·beta[:,g]),  dc[n] = log(s_n) - log(Z_n)
// Tolerance: 2% of ~2.3e9 -> fast transcendentals + 2-term Stirling are safe.
// ---------------------------------------------------------------------------

#define RPB 16   // rows per block in both heavy kernels (fast path: N%RPB==0)

__device__ __forceinline__ float fast_rcp(float x) {
    return __builtin_amdgcn_rcpf(x);
}

// Accurate lgamma (setup / generic fallback only).
__device__ __forceinline__ float lgamma_pos(float x) {
    float lp = 0.0f;
    if (x < 8.0f) {
        float p = x;
        x += 1.0f;
        while (x < 8.0f) { p *= x; x += 1.0f; }
        lp = __logf(p);
    }
    float inv  = fast_rcp(x);
    float inv2 = inv * inv;
    float ser = inv * (0.08333333333f + inv2 * (-0.002777777778f + inv2 * 7.936507937e-4f));
    return (x - 0.5f) * __logf(x) - x + 0.9189385332f + ser - lp;
}

// Hot-loop lgamma: branchless 2-term Stirling (|err|<0.01 for x>=0.5).
__device__ __forceinline__ float stirling_lg(float x) {
    float inv  = fast_rcp(x);
    float inv2 = inv * inv;
    float ser  = inv * (0.08333333333f - 0.002777777778f * inv2);
    return (x - 0.5f) * __logf(x) - x + 0.9189385332f + ser;
}

__device__ __forceinline__ float softplus_f(float x) {
    return fmaxf(x, 0.0f) + log1pf(__expf(-fabsf(x)));
}

__device__ __forceinline__ float wave_reduce(float v) {
#pragma unroll
    for (int off = 32; off; off >>= 1) v += __shfl_down(v, off, 64);
    return v;
}

__device__ __forceinline__ float nb_elem(float y, float lm, float r, float cg,
                                         const float* __restrict__ lgY) {
    float m  = __expf(lm);
    float yr = y + r;
    float lt = __logf(r + m);
    float lg = stirling_lg(yr);
    int   yi = min(__float2int_rz(y), 511);
    return (lg - lgY[yi]) + fmaf(y, lm, -yr * lt) + cg;
}

// ---------------------------------------------------------------------------
// K0 setup: priors + per-gene r[g], cg[g] + lgamma(y+1) table.
// ---------------------------------------------------------------------------
__global__ __launch_bounds__(256) void setup_kernel(
        const float* __restrict__ mu, const float* __restrict__ beta,
        const float* __restrict__ phi, double* __restrict__ acc,
        float* __restrict__ rg, float* __restrict__ cgw,
        float* __restrict__ lgYw, int P, int G) {
    int g = blockIdx.x * 256 + threadIdx.x;
    if (blockIdx.x == 0) {
        for (int i = threadIdx.x; i < 512; i += 256)
            lgYw[i] = lgamma_pos((float)(i + 1));
    }
    float v = 0.0f;
    if (g < G) {
        const float cn = -1.6120857137646180f;  // -0.5*log(8*pi)
        float m = mu[g];
        v = cn - m * m * 0.125f;
        for (int p = 0; p < P; ++p) {
            float b = beta[(size_t)p * G + g];
            v += cn - b * b * 0.125f;
        }
        float sp = softplus_f(phi[g]);
        v += __logf(sp) - sp;
        float r = 1.0f / sp;
        rg[g]  = r;
        cgw[g] = r * __logf(r) - lgamma_pos(r);
    }
    v = wave_reduce(v);
    __shared__ float red[4];
    int lane = threadIdx.x & 63, wid = threadIdx.x >> 6;
    if (lane == 0) red[wid] = v;
    __syncthreads();
    if (threadIdx.x == 0)
        atomicAdd(acc, (double)((red[0] + red[1]) + (red[2] + red[3])));
}

// ---------------------------------------------------------------------------
// K1 (fast, P==4): gene-major row stats. Block = 256 threads x 4 genes,
// loops RPB rows; per-row block partials -> LDS -> one global float atomic.
// beta/mu read once per block (vs once per ROW before): ~5x traffic cut.
// ---------------------------------------------------------------------------
__global__ __launch_bounds__(256) void row_stats_fast(
        const float* __restrict__ X, const float* __restrict__ Y,
        const float* __restrict__ mu, const float* __restrict__ beta,
        float* __restrict__ syw, float* __restrict__ sew, int N, int G) {
    const int G4 = G >> 2;
    const int tid = threadIdx.x;
    const int n0 = blockIdx.y * RPB;
    __shared__ float Xs[RPB * 4];
    __shared__ float syl[RPB], sel[RPB];
    if (tid < RPB * 4) Xs[tid] = X[(size_t)n0 * 4 + tid];
    if (tid < RPB) { syl[tid] = 0.0f; sel[tid] = 0.0f; }

    const int gi = blockIdx.x * 256 + tid;
    const bool active = (gi < G4);
    float4 bb[4];
    float4 mug = {0, 0, 0, 0};
    if (active) {
        const float4* __restrict__ B4 = (const float4*)beta;
#pragma unroll
        for (int p = 0; p < 4; ++p) bb[p] = B4[(size_t)p * G4 + gi];
        mug = ((const float4*)mu)[gi];
    } else {
#pragma unroll
        for (int p = 0; p < 4; ++p) bb[p] = make_float4(0, 0, 0, 0);
    }
    __syncthreads();

    const float4* __restrict__ Yp = (const float4*)Y + (size_t)n0 * G4 + gi;
    const int lane = tid & 63;
#pragma unroll
    for (int i0 = 0; i0 < RPB; i0 += 4) {
        float4 y[4];
#pragma unroll
        for (int j = 0; j < 4; ++j)
            y[j] = active ? Yp[(size_t)(i0 + j) * G4] : make_float4(0, 0, 0, 0);
        float sy[4], se[4];
#pragma unroll
        for (int j = 0; j < 4; ++j) {
            const int i = i0 + j;
            float4 lu = mug;
#pragma unroll
            for (int p = 0; p < 4; ++p) {
                float xp = Xs[i * 4 + p];
                lu.x = fmaf(xp, bb[p].x, lu.x);
                lu.y = fmaf(xp, bb[p].y, lu.y);
                lu.z = fmaf(xp, bb[p].z, lu.z);
                lu.w = fmaf(xp, bb[p].w, lu.w);
            }
            float e = (__expf(lu.x) + __expf(lu.y)) + (__expf(lu.z) + __expf(lu.w));
            se[j] = active ? e : 0.0f;
            sy[j] = (y[j].x + y[j].y) + (y[j].z + y[j].w);
        }
        // 8 interleaved shuffle-reduce chains (ILP hides ds latency)
#pragma unroll
        for (int off = 32; off; off >>= 1) {
#pragma unroll
            for (int j = 0; j < 4; ++j) {
                sy[j] += __shfl_down(sy[j], off, 64);
                se[j] += __shfl_down(se[j], off, 64);
            }
        }
        if (lane == 0) {
#pragma unroll
            for (int j = 0; j < 4; ++j) {
                atomicAdd(&syl[i0 + j], sy[j]);
                atomicAdd(&sel[i0 + j], se[j]);
            }
        }
    }
    __syncthreads();
    if (tid < RPB) {
        atomicAdd(&syw[n0 + tid], syl[tid]);
        atomicAdd(&sew[n0 + tid], sel[tid]);
    }
}

// ---------------------------------------------------------------------------
// K2 (fast, P==4): likelihood. Ring-4 register prefetch of Y rows; dc
// computed in-preamble from sy/se; last block writes the scalar output.
// ---------------------------------------------------------------------------
__global__ __launch_bounds__(256) void nb_loglik_fast(
        const float* __restrict__ X, const float* __restrict__ Y,
        const float* __restrict__ mu, const float* __restrict__ beta,
        const float* __restrict__ rg, const float* __restrict__ cgw,
        const float* __restrict__ lgYw,
        const float* __restrict__ syw, const float* __restrict__ sew,
        double* __restrict__ acc, float* __restrict__ out,
        unsigned int* __restrict__ counter, int N, int G, int nBlocks) {
    __shared__ float lgY[512];
    __shared__ float Xs[RPB * 4];
    __shared__ float dcs[RPB];

    const int tid = threadIdx.x;
    const int n0 = blockIdx.y * RPB;
    const int G4 = G >> 2;

    for (int i = tid; i < 512; i += 256) lgY[i] = lgYw[i];
    if (tid < RPB * 4) Xs[tid] = X[(size_t)n0 * 4 + tid];
    if (tid < RPB) dcs[tid] = __logf(syw[n0 + tid]) - __logf(sew[n0 + tid]);

    const int gi = blockIdx.x * 256 + tid;
    const bool active = (gi < G4);
    float4 bb[4];
    float4 mug = {0, 0, 0, 0}, r4 = {1, 1, 1, 1}, cg4 = {0, 0, 0, 0};
    if (active) {
        const float4* __restrict__ B4 = (const float4*)beta;
#pragma unroll
        for (int p = 0; p < 4; ++p) bb[p] = B4[(size_t)p * G4 + gi];
        mug = ((const float4*)mu)[gi];
        r4  = ((const float4*)rg)[gi];
        cg4 = ((const float4*)cgw)[gi];
    } else {
#pragma unroll
        for (int p = 0; p < 4; ++p) bb[p] = make_float4(0, 0, 0, 0);
    }
    __syncthreads();

    const float4* __restrict__ Yp = (const float4*)Y + (size_t)n0 * G4 + gi;
    float4 yb[4];
#pragma unroll
    for (int j = 0; j < 4; ++j)
        yb[j] = active ? Yp[(size_t)j * G4] : make_float4(0, 0, 0, 0);

    float a0 = 0.0f, a1 = 0.0f, a2 = 0.0f, a3 = 0.0f;
#pragma unroll
    for (int i = 0; i < RPB; ++i) {
        float4 y = yb[i & 3];
        if ((i + 4 < RPB) && active)
            yb[i & 3] = Yp[(size_t)(i + 4) * G4];
        float dcn = dcs[i];
        float4 lu = mug;
#pragma unroll
        for (int p = 0; p < 4; ++p) {
            float xp = Xs[i * 4 + p];
            lu.x = fmaf(xp, bb[p].x, lu.x);
            lu.y = fmaf(xp, bb[p].y, lu.y);
            lu.z = fmaf(xp, bb[p].z, lu.z);
            lu.w = fmaf(xp, bb[p].w, lu.w);
        }
        a0 += nb_elem(y.x, dcn + lu.x, r4.x, cg4.x, lgY);
        a1 += nb_elem(y.y, dcn + lu.y, r4.y, cg4.y, lgY);
        a2 += nb_elem(y.z, dcn + lu.z, r4.z, cg4.z, lgY);
        a3 += nb_elem(y.w, dcn + lu.w, r4.w, cg4.w, lgY);
    }
    float accl = active ? ((a0 + a1) + (a2 + a3)) : 0.0f;
    accl = wave_reduce(accl);
    __shared__ float red[4];
    int lane = tid & 63, wid = tid >> 6;
    if (lane == 0) red[wid] = accl;
    __syncthreads();
    if (tid == 0) {
        atomicAdd(acc, (double)((red[0] + red[1]) + (red[2] + red[3])));
        __threadfence();
        unsigned int old = atomicAdd(counter, 1u);
        if (old == (unsigned int)(nBlocks - 1)) {
            double v = atomicAdd(acc, 0.0);
            out[0] = (float)v;
        }
    }
}

// ---------------------------------------------------------------------------
// Generic fallbacks (correctness only; used if shape assumptions fail).
// ---------------------------------------------------------------------------
__global__ void row_stats_generic(
        const float* __restrict__ X, const float* __restrict__ Y,
        const float* __restrict__ mu, const float* __restrict__ beta,
        float* __restrict__ syw, float* __restrict__ sew, int N, int P, int G) {
    const int n = blockIdx.x;
    const int tid = threadIdx.x;
    float sy = 0.0f, se = 0.0f;
    for (int g = tid; g < G; g += 256) {
        sy += Y[(size_t)n * G + g];
        float lu = mu[g];
        for (int p = 0; p < P; ++p) lu += X[(size_t)n * P + p] * beta[(size_t)p * G + g];
        se += __expf(lu);
    }
    sy = wave_reduce(sy);
    se = wave_reduce(se);
    __shared__ float r1[4], r2[4];
    int lane = tid & 63, wid = tid >> 6;
    if (lane == 0) { r1[wid] = sy; r2[wid] = se; }
    __syncthreads();
    if (tid == 0) {
        syw[n] = (r1[0] + r1[1]) + (r1[2] + r1[3]);
        sew[n] = (r2[0] + r2[1]) + (r2[2] + r2[3]);
    }
}

__global__ void nb_generic(
        const float* __restrict__ X, const float* __restrict__ Y,
        const float* __restrict__ mu, const float* __restrict__ beta,
        const float* __restrict__ rg, const float* __restrict__ cgw,
        const float* __restrict__ syw, const float* __restrict__ sew,
        double* __restrict__ acc, float* __restrict__ out,
        unsigned int* __restrict__ counter, int N, int P, int G) {
    const int n = blockIdx.x;
    const int tid = threadIdx.x;
    float dcn = __logf(syw[n]) - __logf(sew[n]);
    float accl = 0.0f;
    for (int g = tid; g < G; g += 256) {
        float y = Y[(size_t)n * G + g];
        float lu = mu[g];
        for (int p = 0; p < P; ++p) lu += X[(size_t)n * P + p] * beta[(size_t)p * G + g];
        float lm = dcn + lu;
        float r = rg[g];
        float m = __expf(lm);
        accl += stirling_lg(y + r) - lgamma_pos(y + 1.0f)
                + fmaf(y, lm, -(y + r) * __logf(r + m)) + cgw[g];
    }
    accl = wave_reduce(accl);
    __shared__ float red[4];
    int lane = tid & 63, wid = tid >> 6;
    if (lane == 0) red[wid] = accl;
    __syncthreads();
    if (tid == 0) {
        atomicAdd(acc, (double)((red[0] + red[1]) + (red[2] + red[3])));
        __threadfence();
        unsigned int old = atomicAdd(counter, 1u);
        if (old == (unsigned int)(N - 1)) {
            double v = atomicAdd(acc, 0.0);
            out[0] = (float)v;
        }
    }
}

// ---------------------------------------------------------------------------
extern "C" void kernel_launch(void* const* d_in, const int* in_sizes, int n_in,
                              void* d_out, int out_size, void* d_ws, size_t ws_size,
                              hipStream_t stream) {
    const float* X    = (const float*)d_in[0];
    const float* Y    = (const float*)d_in[1];
    const float* mu   = (const float*)d_in[2];
    const float* beta = (const float*)d_in[3];
    const float* phi  = (const float*)d_in[4];
    float* out = (float*)d_out;

    const int G = in_sizes[2];
    const int N = in_sizes[1] / G;
    const int P = in_sizes[0] / N;
    const int G4 = G >> 2;

    // ws layout:
    //   0:     double acc
    //   64:    uint counter
    //   256:   syw [N]   (<= 4096 B for N<=1024)
    //   4352:  sew [N]
    //   8448:  lgY [512]
    //   10496: rg [G]
    //   10496+4G: cg [G]
    char* ws = (char*)d_ws;
    double*       acc     = (double*)ws;
    unsigned int* counter = (unsigned int*)(ws + 64);
    float*        syw     = (float*)(ws + 256);
    float*        sew     = (float*)(ws + 4352);
    float*        lgYw    = (float*)(ws + 8448);
    float*        rgw     = (float*)(ws + 10496);
    float*        cgw     = (float*)(ws + 10496 + (size_t)4 * G);

    hipMemsetAsync(d_ws, 0, 8448, stream);   // acc + counter + sy + se

    int gblocks = (G + 255) / 256;
    setup_kernel<<<gblocks, 256, 0, stream>>>(mu, beta, phi, acc, rgw, cgw, lgYw, P, G);

    if (P == 4 && (G & 3) == 0 && (N % RPB) == 0 && N <= 1024) {
        dim3 grid((G4 + 255) / 256, N / RPB);
        int nBlocks = grid.x * grid.y;
        row_stats_fast<<<grid, 256, 0, stream>>>(X, Y, mu, beta, syw, sew, N, G);
        nb_loglik_fast<<<grid, 256, 0, stream>>>(X, Y, mu, beta, rgw, cgw, lgYw,
                                                 syw, sew, acc, out, counter,
                                                 N, G, nBlocks);
    } else {
        row_stats_generic<<<N, 256, 0, stream>>>(X, Y, mu, beta, syw, sew, N, P, G);
        nb_generic<<<N, 256, 0, stream>>>(X, Y, mu, beta, rgw, cgw, syw, sew,
                                          acc, out, counter, N, P, G);
    }
}

// Round 4
// 174.203 us; speedup vs baseline: 1.2343x; 1.0646x over previous
//
#include <hip/hip_runtime.h>
#include <math.h>

// ---------------------------------------------------------------------------
// NB regression log-posterior, split as:
//   setup:  priors + per-gene r, cg=r*log r - lgamma(r) + lgamma-table
//   pre:    se[n] = sum_g exp(mu+X.beta)   (no Y)
//           sy[n] = sum_g Y[n,g]           (pure Y stream)
//           acc  += -sum lgamma(y+1)       (Y-only term, hoisted out of K2)
//   K2:     sum_{n,g} [ stirling(y+r) + y*lm - (y+r)*log(r+m) + cg ],
//           lm = dc[n]+mu+X.beta, dc = log sy - log se, m = exp(lm)
//   finalize: out = (float)acc
// Tolerance: 2% of ~2.3e9 -> fast transcendentals + 2-term Stirling are safe.
// ---------------------------------------------------------------------------

#define RPB 16   // rows per block in heavy kernels (fast path: N%RPB==0)

__device__ __forceinline__ float fast_rcp(float x) {
    return __builtin_amdgcn_rcpf(x);
}

// Accurate lgamma (setup / generic fallback only).
__device__ __forceinline__ float lgamma_pos(float x) {
    float lp = 0.0f;
    if (x < 8.0f) {
        float p = x;
        x += 1.0f;
        while (x < 8.0f) { p *= x; x += 1.0f; }
        lp = __logf(p);
    }
    float inv  = fast_rcp(x);
    float inv2 = inv * inv;
    float ser = inv * (0.08333333333f + inv2 * (-0.002777777778f + inv2 * 7.936507937e-4f));
    return (x - 0.5f) * __logf(x) - x + 0.9189385332f + ser - lp;
}

// Hot-loop lgamma: branchless 2-term Stirling (|err|<0.01 for x>=0.5).
__device__ __forceinline__ float stirling_lg(float x) {
    float inv  = fast_rcp(x);
    float inv2 = inv * inv;
    float ser  = inv * (0.08333333333f - 0.002777777778f * inv2);
    return (x - 0.5f) * __logf(x) - x + 0.9189385332f + ser;
}

__device__ __forceinline__ float softplus_f(float x) {
    return fmaxf(x, 0.0f) + log1pf(__expf(-fabsf(x)));
}

__device__ __forceinline__ float wave_reduce(float v) {
#pragma unroll
    for (int off = 32; off; off >>= 1) v += __shfl_down(v, off, 64);
    return v;
}

// ---------------------------------------------------------------------------
// K0 setup: priors + per-gene r[g], cg[g] + lgamma(y+1) table in ws.
// ---------------------------------------------------------------------------
__global__ __launch_bounds__(256) void setup_kernel(
        const float* __restrict__ mu, const float* __restrict__ beta,
        const float* __restrict__ phi, double* __restrict__ acc,
        float* __restrict__ rg, float* __restrict__ cgw,
        float* __restrict__ lgYw, int P, int G) {
    int g = blockIdx.x * 256 + threadIdx.x;
    if (blockIdx.x == 0) {
        for (int i = threadIdx.x; i < 512; i += 256)
            lgYw[i] = lgamma_pos((float)(i + 1));
    }
    float v = 0.0f;
    if (g < G) {
        const float cn = -1.6120857137646180f;  // -0.5*log(8*pi)
        float m = mu[g];
        v = cn - m * m * 0.125f;
        for (int p = 0; p < P; ++p) {
            float b = beta[(size_t)p * G + g];
            v += cn - b * b * 0.125f;
        }
        float sp = softplus_f(phi[g]);
        v += __logf(sp) - sp;
        float r = 1.0f / sp;
        rg[g]  = r;
        cgw[g] = r * __logf(r) - lgamma_pos(r);
    }
    v = wave_reduce(v);
    __shared__ float red[4];
    int lane = threadIdx.x & 63, wid = threadIdx.x >> 6;
    if (lane == 0) red[wid] = v;
    __syncthreads();
    if (threadIdx.x == 0)
        atomicAdd(acc, (double)((red[0] + red[1]) + (red[2] + red[3])));
}

// ---------------------------------------------------------------------------
// K1 pre (fast, P==4): se[n] (no Y), sy[n] (Y stream), -sum lgamma(y+1).
// Gene-major: beta/mu loaded once per block, 16 rows per block.
// ---------------------------------------------------------------------------
__global__ __launch_bounds__(256) void pre_fast(
        const float* __restrict__ X, const float* __restrict__ Y,
        const float* __restrict__ mu, const float* __restrict__ beta,
        const float* __restrict__ lgYw,
        float* __restrict__ syw, float* __restrict__ sew,
        double* __restrict__ acc, int N, int G) {
    const int G4 = G >> 2;
    const int tid = threadIdx.x;
    const int n0 = blockIdx.y * RPB;
    __shared__ float lgY[512];
    __shared__ float Xs[RPB * 4];
    __shared__ float syl[RPB], sel[RPB];
    for (int i = tid; i < 512; i += 256) lgY[i] = lgYw[i];
    if (tid < RPB * 4) Xs[tid] = X[(size_t)n0 * 4 + tid];
    if (tid < RPB) { syl[tid] = 0.0f; sel[tid] = 0.0f; }

    const int gi = blockIdx.x * 256 + tid;
    const bool active = (gi < G4);
    float4 bb[4];
    float4 mug = {0, 0, 0, 0};
    if (active) {
        const float4* __restrict__ B4 = (const float4*)beta;
#pragma unroll
        for (int p = 0; p < 4; ++p) bb[p] = B4[(size_t)p * G4 + gi];
        mug = ((const float4*)mu)[gi];
    } else {
#pragma unroll
        for (int p = 0; p < 4; ++p) bb[p] = make_float4(0, 0, 0, 0);
    }
    __syncthreads();

    const float4* __restrict__ Yp = (const float4*)Y + (size_t)n0 * G4 + gi;
    const int lane = tid & 63;
    float lgacc = 0.0f;
#pragma unroll
    for (int i0 = 0; i0 < RPB; i0 += 4) {
        float4 y[4];
#pragma unroll
        for (int j = 0; j < 4; ++j)
            y[j] = active ? Yp[(size_t)(i0 + j) * G4] : make_float4(0, 0, 0, 0);
        float sy[4], se[4];
#pragma unroll
        for (int j = 0; j < 4; ++j) {
            const int i = i0 + j;
            float4 lu = mug;
#pragma unroll
            for (int p = 0; p < 4; ++p) {
                float xp = Xs[i * 4 + p];
                lu.x = fmaf(xp, bb[p].x, lu.x);
                lu.y = fmaf(xp, bb[p].y, lu.y);
                lu.z = fmaf(xp, bb[p].z, lu.z);
                lu.w = fmaf(xp, bb[p].w, lu.w);
            }
            float e = (__expf(lu.x) + __expf(lu.y)) + (__expf(lu.z) + __expf(lu.w));
            se[j] = active ? e : 0.0f;
            sy[j] = (y[j].x + y[j].y) + (y[j].z + y[j].w);
            if (active) {
                lgacc += (lgY[min(__float2int_rz(y[j].x), 511)]
                        + lgY[min(__float2int_rz(y[j].y), 511)])
                       + (lgY[min(__float2int_rz(y[j].z), 511)]
                        + lgY[min(__float2int_rz(y[j].w), 511)]);
            }
        }
#pragma unroll
        for (int off = 32; off; off >>= 1) {
#pragma unroll
            for (int j = 0; j < 4; ++j) {
                sy[j] += __shfl_down(sy[j], off, 64);
                se[j] += __shfl_down(se[j], off, 64);
            }
        }
        if (lane == 0) {
#pragma unroll
            for (int j = 0; j < 4; ++j) {
                atomicAdd(&syl[i0 + j], sy[j]);
                atomicAdd(&sel[i0 + j], se[j]);
            }
        }
    }
    lgacc = wave_reduce(lgacc);
    __shared__ float red[4];
    int wid = tid >> 6;
    if (lane == 0) red[wid] = lgacc;
    __syncthreads();
    if (tid < RPB) {
        atomicAdd(&syw[n0 + tid], syl[tid]);
        atomicAdd(&sew[n0 + tid], sel[tid]);
    }
    if (tid == 0)
        atomicAdd(acc, -(double)((red[0] + red[1]) + (red[2] + red[3])));
}

// ---------------------------------------------------------------------------
// K2 (fast, P==4): main likelihood terms; no LDS table, no fence/counter.
// Ring-4 register prefetch of Y rows; dc computed in-preamble.
// ---------------------------------------------------------------------------
__global__ __launch_bounds__(256) void nb_loglik_fast(
        const float* __restrict__ X, const float* __restrict__ Y,
        const float* __restrict__ mu, const float* __restrict__ beta,
        const float* __restrict__ rg, const float* __restrict__ cgw,
        const float* __restrict__ syw, const float* __restrict__ sew,
        double* __restrict__ acc, int N, int G) {
    __shared__ float Xs[RPB * 4];
    __shared__ float dcs[RPB];

    const int tid = threadIdx.x;
    const int n0 = blockIdx.y * RPB;
    const int G4 = G >> 2;

    if (tid < RPB * 4) Xs[tid] = X[(size_t)n0 * 4 + tid];
    if (tid < RPB) dcs[tid] = __logf(syw[n0 + tid]) - __logf(sew[n0 + tid]);

    const int gi = blockIdx.x * 256 + tid;
    const bool active = (gi < G4);
    float4 bb[4];
    float4 mug = {0, 0, 0, 0}, r4 = {1, 1, 1, 1}, cg4 = {0, 0, 0, 0};
    if (active) {
        const float4* __restrict__ B4 = (const float4*)beta;
#pragma unroll
        for (int p = 0; p < 4; ++p) bb[p] = B4[(size_t)p * G4 + gi];
        mug = ((const float4*)mu)[gi];
        r4  = ((const float4*)rg)[gi];
        cg4 = ((const float4*)cgw)[gi];
    } else {
#pragma unroll
        for (int p = 0; p < 4; ++p) bb[p] = make_float4(0, 0, 0, 0);
    }
    __syncthreads();

    const float4* __restrict__ Yp = (const float4*)Y + (size_t)n0 * G4 + gi;
    float4 yb[4];
#pragma unroll
    for (int j = 0; j < 4; ++j)
        yb[j] = active ? Yp[(size_t)j * G4] : make_float4(0, 0, 0, 0);

    float a0 = 0.0f, a1 = 0.0f, a2 = 0.0f, a3 = 0.0f;
#pragma unroll
    for (int i = 0; i < RPB; ++i) {
        float4 y = yb[i & 3];
        if ((i + 4 < RPB) && active)
            yb[i & 3] = Yp[(size_t)(i + 4) * G4];
        float dcn = dcs[i];
        float4 lu = mug;
#pragma unroll
        for (int p = 0; p < 4; ++p) {
            float xp = Xs[i * 4 + p];
            lu.x = fmaf(xp, bb[p].x, lu.x);
            lu.y = fmaf(xp, bb[p].y, lu.y);
            lu.z = fmaf(xp, bb[p].z, lu.z);
            lu.w = fmaf(xp, bb[p].w, lu.w);
        }
        float lm, m, yr;
        lm = dcn + lu.x; m = __expf(lm); yr = y.x + r4.x;
        a0 += stirling_lg(yr) + fmaf(y.x, lm, -yr * __logf(r4.x + m)) + cg4.x;
        lm = dcn + lu.y; m = __expf(lm); yr = y.y + r4.y;
        a1 += stirling_lg(yr) + fmaf(y.y, lm, -yr * __logf(r4.y + m)) + cg4.y;
        lm = dcn + lu.z; m = __expf(lm); yr = y.z + r4.z;
        a2 += stirling_lg(yr) + fmaf(y.z, lm, -yr * __logf(r4.z + m)) + cg4.z;
        lm = dcn + lu.w; m = __expf(lm); yr = y.w + r4.w;
        a3 += stirling_lg(yr) + fmaf(y.w, lm, -yr * __logf(r4.w + m)) + cg4.w;
    }
    float accl = active ? ((a0 + a1) + (a2 + a3)) : 0.0f;
    accl = wave_reduce(accl);
    __shared__ float red[4];
    int lane = tid & 63, wid = tid >> 6;
    if (lane == 0) red[wid] = accl;
    __syncthreads();
    if (tid == 0)
        atomicAdd(acc, (double)((red[0] + red[1]) + (red[2] + red[3])));
}

__global__ void finalize_kernel(const double* __restrict__ acc, float* __restrict__ out) {
    out[0] = (float)acc[0];
}

// ---------------------------------------------------------------------------
// Generic fallbacks (correctness only).
// ---------------------------------------------------------------------------
__global__ void row_stats_generic(
        const float* __restrict__ X, const float* __restrict__ Y,
        const float* __restrict__ mu, const float* __restrict__ beta,
        float* __restrict__ syw, float* __restrict__ sew, int N, int P, int G) {
    const int n = blockIdx.x;
    const int tid = threadIdx.x;
    float sy = 0.0f, se = 0.0f;
    for (int g = tid; g < G; g += 256) {
        sy += Y[(size_t)n * G + g];
        float lu = mu[g];
        for (int p = 0; p < P; ++p) lu += X[(size_t)n * P + p] * beta[(size_t)p * G + g];
        se += __expf(lu);
    }
    sy = wave_reduce(sy);
    se = wave_reduce(se);
    __shared__ float r1[4], r2[4];
    int lane = tid & 63, wid = tid >> 6;
    if (lane == 0) { r1[wid] = sy; r2[wid] = se; }
    __syncthreads();
    if (tid == 0) {
        syw[n] = (r1[0] + r1[1]) + (r1[2] + r1[3]);
        sew[n] = (r2[0] + r2[1]) + (r2[2] + r2[3]);
    }
}

__global__ void nb_generic(
        const float* __restrict__ X, const float* __restrict__ Y,
        const float* __restrict__ mu, const float* __restrict__ beta,
        const float* __restrict__ rg, const float* __restrict__ cgw,
        const float* __restrict__ syw, const float* __restrict__ sew,
        double* __restrict__ acc, int N, int P, int G) {
    const int n = blockIdx.x;
    const int tid = threadIdx.x;
    float dcn = __logf(syw[n]) - __logf(sew[n]);
    float accl = 0.0f;
    for (int g = tid; g < G; g += 256) {
        float y = Y[(size_t)n * G + g];
        float lu = mu[g];
        for (int p = 0; p < P; ++p) lu += X[(size_t)n * P + p] * beta[(size_t)p * G + g];
        float lm = dcn + lu;
        float r = rg[g];
        float m = __expf(lm);
        accl += stirling_lg(y + r) - lgamma_pos(y + 1.0f)
                + fmaf(y, lm, -(y + r) * __logf(r + m)) + cgw[g];
    }
    accl = wave_reduce(accl);
    __shared__ float red[4];
    int lane = tid & 63, wid = tid >> 6;
    if (lane == 0) red[wid] = accl;
    __syncthreads();
    if (tid == 0)
        atomicAdd(acc, (double)((red[0] + red[1]) + (red[2] + red[3])));
}

// ---------------------------------------------------------------------------
extern "C" void kernel_launch(void* const* d_in, const int* in_sizes, int n_in,
                              void* d_out, int out_size, void* d_ws, size_t ws_size,
                              hipStream_t stream) {
    const float* X    = (const float*)d_in[0];
    const float* Y    = (const float*)d_in[1];
    const float* mu   = (const float*)d_in[2];
    const float* beta = (const float*)d_in[3];
    const float* phi  = (const float*)d_in[4];
    float* out = (float*)d_out;

    const int G = in_sizes[2];
    const int N = in_sizes[1] / G;
    const int P = in_sizes[0] / N;
    const int G4 = G >> 2;

    // ws layout:
    //   0:     double acc
    //   256:   syw [N]
    //   4352:  sew [N]
    //   8448:  lgY [512]
    //   10496: rg [G]
    //   10496+4G: cg [G]
    char* ws = (char*)d_ws;
    double* acc  = (double*)ws;
    float*  syw  = (float*)(ws + 256);
    float*  sew  = (float*)(ws + 4352);
    float*  lgYw = (float*)(ws + 8448);
    float*  rgw  = (float*)(ws + 10496);
    float*  cgw  = (float*)(ws + 10496 + (size_t)4 * G);

    hipMemsetAsync(d_ws, 0, 8448, stream);   // acc + sy + se

    int gblocks = (G + 255) / 256;
    setup_kernel<<<gblocks, 256, 0, stream>>>(mu, beta, phi, acc, rgw, cgw, lgYw, P, G);

    if (P == 4 && (G & 3) == 0 && (N % RPB) == 0 && N <= 1024) {
        dim3 grid((G4 + 255) / 256, N / RPB);
        pre_fast<<<grid, 256, 0, stream>>>(X, Y, mu, beta, lgYw, syw, sew, acc, N, G);
        nb_loglik_fast<<<grid, 256, 0, stream>>>(X, Y, mu, beta, rgw, cgw,
                                                 syw, sew, acc, N, G);
    } else {
        row_stats_generic<<<N, 256, 0, stream>>>(X, Y, mu, beta, syw, sew, N, P, G);
        nb_generic<<<N, 256, 0, stream>>>(X, Y, mu, beta, rgw, cgw, syw, sew,
                                          acc, N, P, G);
    }
    finalize_kernel<<<1, 1, 0, stream>>>(acc, out);
}

// Round 5
// 173.180 us; speedup vs baseline: 1.2416x; 1.0059x over previous
//
#include <hip/hip_runtime.h>
#include <math.h>

// ---------------------------------------------------------------------------
// NB regression log-posterior, split as:
//   setup:  priors + per-gene r, cg = r*log r - lgamma(r)
//   pre:    se[n] = sum_g exp(mu+X.beta)   (no Y)
//           sy[n] = sum_g Y[n,g]           (Y stream)
//           acc  += -sum lgamma(y+1)       (Y-only term, hoisted out of K2)
//   K2:     sum_{n,g} [ stirling(y+r) + y*lm - (y+r)*log(r+m) + cg ],
//           lm = dc[n]+mu+X.beta, dc = log sy - log se, m = exp(lm)
//   finalize: out = (float)acc
// Tolerance: 2% of ~2.3e9 -> fast transcendentals + 2-term Stirling are safe.
//
// R4 theory: kernels are memory-LATENCY x outstanding-miss bound (warm replay
// with ~0 HBM traffic still took 60 us). Fix: ring-8 prefetch (8 outstanding
// 16B loads/lane) + VGPR <= ~85 so all 5120 waves are co-resident (6/SIMD
// allowed, 5/SIMD used -> single-round schedule, no tail).
// ---------------------------------------------------------------------------

#define RPB 16   // rows per block in heavy kernels (fast path: N%RPB==0)

__device__ __forceinline__ float fast_rcp(float x) {
    return __builtin_amdgcn_rcpf(x);
}

// Accurate lgamma (setup / preamble / generic fallback only).
__device__ __forceinline__ float lgamma_pos(float x) {
    float lp = 0.0f;
    if (x < 8.0f) {
        float p = x;
        x += 1.0f;
        while (x < 8.0f) { p *= x; x += 1.0f; }
        lp = __logf(p);
    }
    float inv  = fast_rcp(x);
    float inv2 = inv * inv;
    float ser = inv * (0.08333333333f + inv2 * (-0.002777777778f + inv2 * 7.936507937e-4f));
    return (x - 0.5f) * __logf(x) - x + 0.9189385332f + ser - lp;
}

// Hot-loop lgamma: branchless 2-term Stirling (|err|<0.01 for x>=0.5).
__device__ __forceinline__ float stirling_lg(float x) {
    float inv  = fast_rcp(x);
    float inv2 = inv * inv;
    float ser  = inv * (0.08333333333f - 0.002777777778f * inv2);
    return (x - 0.5f) * __logf(x) - x + 0.9189385332f + ser;
}

__device__ __forceinline__ float softplus_f(float x) {
    return fmaxf(x, 0.0f) + log1pf(__expf(-fabsf(x)));
}

__device__ __forceinline__ float wave_reduce(float v) {
#pragma unroll
    for (int off = 32; off; off >>= 1) v += __shfl_down(v, off, 64);
    return v;
}

// ---------------------------------------------------------------------------
// K0 setup: priors + per-gene r[g], cg[g].
// ---------------------------------------------------------------------------
__global__ __launch_bounds__(256) void setup_kernel(
        const float* __restrict__ mu, const float* __restrict__ beta,
        const float* __restrict__ phi, double* __restrict__ acc,
        float* __restrict__ rg, float* __restrict__ cgw, int P, int G) {
    int g = blockIdx.x * 256 + threadIdx.x;
    float v = 0.0f;
    if (g < G) {
        const float cn = -1.6120857137646180f;  // -0.5*log(8*pi)
        float m = mu[g];
        v = cn - m * m * 0.125f;
        for (int p = 0; p < P; ++p) {
            float b = beta[(size_t)p * G + g];
            v += cn - b * b * 0.125f;
        }
        float sp = softplus_f(phi[g]);
        v += __logf(sp) - sp;
        float r = 1.0f / sp;
        rg[g]  = r;
        cgw[g] = r * __logf(r) - lgamma_pos(r);
    }
    v = wave_reduce(v);
    __shared__ float red[4];
    int lane = threadIdx.x & 63, wid = threadIdx.x >> 6;
    if (lane == 0) red[wid] = v;
    __syncthreads();
    if (threadIdx.x == 0)
        atomicAdd(acc, (double)((red[0] + red[1]) + (red[2] + red[3])));
}

// ---------------------------------------------------------------------------
// K1 pre (fast, P==4): se[n] (no Y), sy[n] (Y stream), -sum lgamma(y+1).
// Gene-major, ring-8 Y prefetch, lgamma table computed in-LDS.
// ---------------------------------------------------------------------------
__global__ __launch_bounds__(256) void pre_fast(
        const float* __restrict__ X, const float* __restrict__ Y,
        const float* __restrict__ mu, const float* __restrict__ beta,
        float* __restrict__ syw, float* __restrict__ sew,
        double* __restrict__ acc, int N, int G) {
    const int G4 = G >> 2;
    const int tid = threadIdx.x;
    const int n0 = blockIdx.y * RPB;
    __shared__ float lgY[512];
    __shared__ float Xs[RPB * 4];
    __shared__ float syl[RPB], sel[RPB];
    for (int i = tid; i < 512; i += 256) lgY[i] = lgamma_pos((float)(i + 1));
    if (tid < RPB * 4) Xs[tid] = X[(size_t)n0 * 4 + tid];
    if (tid < RPB) { syl[tid] = 0.0f; sel[tid] = 0.0f; }

    const int gi = blockIdx.x * 256 + tid;
    const bool active = (gi < G4);
    const float4 zero = make_float4(0, 0, 0, 0);
    float4 bb[4];
    float4 mug = zero;
    if (active) {
        const float4* __restrict__ B4 = (const float4*)beta;
#pragma unroll
        for (int p = 0; p < 4; ++p) bb[p] = B4[(size_t)p * G4 + gi];
        mug = ((const float4*)mu)[gi];
    } else {
#pragma unroll
        for (int p = 0; p < 4; ++p) bb[p] = zero;
    }
    __syncthreads();

    const float4* __restrict__ Yp = (const float4*)Y + (size_t)n0 * G4 + gi;
    const int lane = tid & 63;

    float4 yb[8];
#pragma unroll
    for (int j = 0; j < 8; ++j)
        yb[j] = active ? Yp[(size_t)j * G4] : zero;

    float lgacc = 0.0f;
#pragma unroll
    for (int i0 = 0; i0 < RPB; i0 += 4) {
        float sy[4], se[4];
#pragma unroll
        for (int j = 0; j < 4; ++j) {
            const int i = i0 + j;
            float4 y = yb[i & 7];
            if ((i + 8 < RPB) && active)
                yb[i & 7] = Yp[(size_t)(i + 8) * G4];
            float4 lu = mug;
#pragma unroll
            for (int p = 0; p < 4; ++p) {
                float xp = Xs[i * 4 + p];
                lu.x = fmaf(xp, bb[p].x, lu.x);
                lu.y = fmaf(xp, bb[p].y, lu.y);
                lu.z = fmaf(xp, bb[p].z, lu.z);
                lu.w = fmaf(xp, bb[p].w, lu.w);
            }
            float e = (__expf(lu.x) + __expf(lu.y)) + (__expf(lu.z) + __expf(lu.w));
            se[j] = active ? e : 0.0f;
            sy[j] = (y.x + y.y) + (y.z + y.w);
            if (active) {
                lgacc += (lgY[min(__float2int_rz(y.x), 511)]
                        + lgY[min(__float2int_rz(y.y), 511)])
                       + (lgY[min(__float2int_rz(y.z), 511)]
                        + lgY[min(__float2int_rz(y.w), 511)]);
            }
        }
        // 8 interleaved shuffle-reduce chains
#pragma unroll
        for (int off = 32; off; off >>= 1) {
#pragma unroll
            for (int j = 0; j < 4; ++j) {
                sy[j] += __shfl_down(sy[j], off, 64);
                se[j] += __shfl_down(se[j], off, 64);
            }
        }
        if (lane == 0) {
#pragma unroll
            for (int j = 0; j < 4; ++j) {
                atomicAdd(&syl[i0 + j], sy[j]);
                atomicAdd(&sel[i0 + j], se[j]);
            }
        }
    }
    lgacc = wave_reduce(lgacc);
    __shared__ float red[4];
    int wid = tid >> 6;
    if (lane == 0) red[wid] = lgacc;
    __syncthreads();
    if (tid < RPB) {
        atomicAdd(&syw[n0 + tid], syl[tid]);
        atomicAdd(&sew[n0 + tid], sel[tid]);
    }
    if (tid == 0)
        atomicAdd(acc, -(double)((red[0] + red[1]) + (red[2] + red[3])));
}

// ---------------------------------------------------------------------------
// K2 (fast, P==4): main likelihood. Ring-8 Y prefetch; dc in-preamble.
// ---------------------------------------------------------------------------
__global__ __launch_bounds__(256) void nb_loglik_fast(
        const float* __restrict__ X, const float* __restrict__ Y,
        const float* __restrict__ mu, const float* __restrict__ beta,
        const float* __restrict__ rg, const float* __restrict__ cgw,
        const float* __restrict__ syw, const float* __restrict__ sew,
        double* __restrict__ acc, int N, int G) {
    __shared__ float Xs[RPB * 4];
    __shared__ float dcs[RPB];

    const int tid = threadIdx.x;
    const int n0 = blockIdx.y * RPB;
    const int G4 = G >> 2;

    if (tid < RPB * 4) Xs[tid] = X[(size_t)n0 * 4 + tid];
    if (tid < RPB) dcs[tid] = __logf(syw[n0 + tid]) - __logf(sew[n0 + tid]);

    const int gi = blockIdx.x * 256 + tid;
    const bool active = (gi < G4);
    const float4 zero = make_float4(0, 0, 0, 0);
    float4 bb[4];
    float4 mug = zero, r4 = make_float4(1, 1, 1, 1), cg4 = zero;
    if (active) {
        const float4* __restrict__ B4 = (const float4*)beta;
#pragma unroll
        for (int p = 0; p < 4; ++p) bb[p] = B4[(size_t)p * G4 + gi];
        mug = ((const float4*)mu)[gi];
        r4  = ((const float4*)rg)[gi];
        cg4 = ((const float4*)cgw)[gi];
    } else {
#pragma unroll
        for (int p = 0; p < 4; ++p) bb[p] = zero;
    }
    __syncthreads();

    const float4* __restrict__ Yp = (const float4*)Y + (size_t)n0 * G4 + gi;
    float4 yb[8];
#pragma unroll
    for (int j = 0; j < 8; ++j)
        yb[j] = active ? Yp[(size_t)j * G4] : zero;

    float a0 = 0.0f, a1 = 0.0f, a2 = 0.0f, a3 = 0.0f;
#pragma unroll
    for (int i = 0; i < RPB; ++i) {
        float4 y = yb[i & 7];
        if ((i + 8 < RPB) && active)
            yb[i & 7] = Yp[(size_t)(i + 8) * G4];
        float dcn = dcs[i];
        float4 lu = mug;
#pragma unroll
        for (int p = 0; p < 4; ++p) {
            float xp = Xs[i * 4 + p];
            lu.x = fmaf(xp, bb[p].x, lu.x);
            lu.y = fmaf(xp, bb[p].y, lu.y);
            lu.z = fmaf(xp, bb[p].z, lu.z);
            lu.w = fmaf(xp, bb[p].w, lu.w);
        }
        float lm, m, yr;
        lm = dcn + lu.x; m = __expf(lm); yr = y.x + r4.x;
        a0 += stirling_lg(yr) + fmaf(y.x, lm, -yr * __logf(r4.x + m)) + cg4.x;
        lm = dcn + lu.y; m = __expf(lm); yr = y.y + r4.y;
        a1 += stirling_lg(yr) + fmaf(y.y, lm, -yr * __logf(r4.y + m)) + cg4.y;
        lm = dcn + lu.z; m = __expf(lm); yr = y.z + r4.z;
        a2 += stirling_lg(yr) + fmaf(y.z, lm, -yr * __logf(r4.z + m)) + cg4.z;
        lm = dcn + lu.w; m = __expf(lm); yr = y.w + r4.w;
        a3 += stirling_lg(yr) + fmaf(y.w, lm, -yr * __logf(r4.w + m)) + cg4.w;
    }
    float accl = active ? ((a0 + a1) + (a2 + a3)) : 0.0f;
    accl = wave_reduce(accl);
    __shared__ float red[4];
    int lane = tid & 63, wid = tid >> 6;
    if (lane == 0) red[wid] = accl;
    __syncthreads();
    if (tid == 0)
        atomicAdd(acc, (double)((red[0] + red[1]) + (red[2] + red[3])));
}

__global__ void finalize_kernel(const double* __restrict__ acc, float* __restrict__ out) {
    out[0] = (float)acc[0];
}

// ---------------------------------------------------------------------------
// Generic fallbacks (correctness only).
// ---------------------------------------------------------------------------
__global__ void row_stats_generic(
        const float* __restrict__ X, const float* __restrict__ Y,
        const float* __restrict__ mu, const float* __restrict__ beta,
        float* __restrict__ syw, float* __restrict__ sew, int N, int P, int G) {
    const int n = blockIdx.x;
    const int tid = threadIdx.x;
    float sy = 0.0f, se = 0.0f;
    for (int g = tid; g < G; g += 256) {
        sy += Y[(size_t)n * G + g];
        float lu = mu[g];
        for (int p = 0; p < P; ++p) lu += X[(size_t)n * P + p] * beta[(size_t)p * G + g];
        se += __expf(lu);
    }
    sy = wave_reduce(sy);
    se = wave_reduce(se);
    __shared__ float r1[4], r2[4];
    int lane = tid & 63, wid = tid >> 6;
    if (lane == 0) { r1[wid] = sy; r2[wid] = se; }
    __syncthreads();
    if (tid == 0) {
        syw[n] = (r1[0] + r1[1]) + (r1[2] + r1[3]);
        sew[n] = (r2[0] + r2[1]) + (r2[2] + r2[3]);
    }
}

__global__ void nb_generic(
        const float* __restrict__ X, const float* __restrict__ Y,
        const float* __restrict__ mu, const float* __restrict__ beta,
        const float* __restrict__ rg, const float* __restrict__ cgw,
        const float* __restrict__ syw, const float* __restrict__ sew,
        double* __restrict__ acc, int N, int P, int G) {
    const int n = blockIdx.x;
    const int tid = threadIdx.x;
    float dcn = __logf(syw[n]) - __logf(sew[n]);
    float accl = 0.0f;
    for (int g = tid; g < G; g += 256) {
        float y = Y[(size_t)n * G + g];
        float lu = mu[g];
        for (int p = 0; p < P; ++p) lu += X[(size_t)n * P + p] * beta[(size_t)p * G + g];
        float lm = dcn + lu;
        float r = rg[g];
        float m = __expf(lm);
        accl += stirling_lg(y + r) - lgamma_pos(y + 1.0f)
                + fmaf(y, lm, -(y + r) * __logf(r + m)) + cgw[g];
    }
    accl = wave_reduce(accl);
    __shared__ float red[4];
    int lane = tid & 63, wid = tid >> 6;
    if (lane == 0) red[wid] = accl;
    __syncthreads();
    if (tid == 0)
        atomicAdd(acc, (double)((red[0] + red[1]) + (red[2] + red[3])));
}

// ---------------------------------------------------------------------------
extern "C" void kernel_launch(void* const* d_in, const int* in_sizes, int n_in,
                              void* d_out, int out_size, void* d_ws, size_t ws_size,
                              hipStream_t stream) {
    const float* X    = (const float*)d_in[0];
    const float* Y    = (const float*)d_in[1];
    const float* mu   = (const float*)d_in[2];
    const float* beta = (const float*)d_in[3];
    const float* phi  = (const float*)d_in[4];
    float* out = (float*)d_out;

    const int G = in_sizes[2];
    const int N = in_sizes[1] / G;
    const int P = in_sizes[0] / N;
    const int G4 = G >> 2;

    // ws layout:
    //   0:     double acc
    //   256:   syw [N]
    //   4352:  sew [N]
    //   8448:  rg [G]
    //   8448+4G: cg [G]
    char* ws = (char*)d_ws;
    double* acc  = (double*)ws;
    float*  syw  = (float*)(ws + 256);
    float*  sew  = (float*)(ws + 4352);
    float*  rgw  = (float*)(ws + 8448);
    float*  cgw  = (float*)(ws + 8448 + (size_t)4 * G);

    hipMemsetAsync(d_ws, 0, 8448, stream);   // acc + sy + se

    int gblocks = (G + 255) / 256;

    if (P == 4 && (G & 3) == 0 && (N % RPB) == 0 && N <= 1024) {
        dim3 grid((G4 + 255) / 256, N / RPB);
        // pre has no dependency on setup now; start the big kernel first.
        pre_fast<<<grid, 256, 0, stream>>>(X, Y, mu, beta, syw, sew, acc, N, G);
        setup_kernel<<<gblocks, 256, 0, stream>>>(mu, beta, phi, acc, rgw, cgw, P, G);
        nb_loglik_fast<<<grid, 256, 0, stream>>>(X, Y, mu, beta, rgw, cgw,
                                                 syw, sew, acc, N, G);
    } else {
        setup_kernel<<<gblocks, 256, 0, stream>>>(mu, beta, phi, acc, rgw, cgw, P, G);
        row_stats_generic<<<N, 256, 0, stream>>>(X, Y, mu, beta, syw, sew, N, P, G);
        nb_generic<<<N, 256, 0, stream>>>(X, Y, mu, beta, rgw, cgw, syw, sew,
                                          acc, N, P, G);
    }
    finalize_kernel<<<1, 1, 0, stream>>>(acc, out);
}